// Round 4
// baseline (725.340 us; speedup 1.0000x reference)
//
#include <hip/hip_runtime.h>

// PointerNet: B=4, N=128, H=512, d_pair=256.
// Interface (verified):
//   inputs  f32, setup_inputs dict order
//   d_out   f32, 50,724,864 elements = [4][128][128][774]
// Per mlp g in {future(Wf1,Wf2,w3), hist1(Wh1a,Wh1b,wl1), hist2(Wh2a,Wh2b,wl2)}:
//   uv[m][c'] = sum_h P[m][h] * W1[(c'>=1024?512:0)+h][c'&1023]     (m = b*128+i)
//   y[bi,j,n] = relu( sum_k relu(uv[bi][k] + uv[bj][1024+k]) * W2[k][n] )
//   p = softmax_c( sum_n y[n] * w3[n][c] )
//   out[((bi)*128+j)*774 + g*258 + {n | 256+c}] = {y | p}
//
// R12 changes: (a) pair wave tile 32jx128n -> 64jx64n (same 64-reg acc, B
// ds_reads halved: the LDS read port was co-limiting with MFMA), setprio(1)
// around MFMA cluster. (b) launch fusion: 12 dispatches -> 3 (prep_all +
// stage1_mfma3 + pair_mfma3) on ws>=27MiB, tiered fallbacks below that.
//
// Workspace tiers:
//   full (ws>=27M): uv_all 12M @0 | w2f_all 3M @12M | w1f_all 12M @15M
//   mid  (ws>=9M):  uv 4M @0 | w2f 1M @4M | w1f 4M @5M   (per-mlp launches)
//   low  (ws>=5M):  uv 4M @0 | w2f 1M @4M                (stage1_valu)
//   else: all-VALU path + head_kernel

typedef __attribute__((ext_vector_type(4))) float floatx4;
typedef __attribute__((ext_vector_type(2))) float floatx2;
typedef __attribute__((ext_vector_type(8))) short short8;

#define KT 16
#define LSTRIDE 68  // 64 + 4 pad (LDS bank-conflict break)
#define MB (1u << 20)

__device__ __forceinline__ void gload_lds16(const void* g, void* l) {
  __builtin_amdgcn_global_load_lds(
      (const __attribute__((address_space(1))) void*)g,
      (__attribute__((address_space(3))) void*)l, 16, 0, 0);
}

// Split 8 f32 into bf16 hi (truncated) + bf16 lo (exact remainder, truncated).
__device__ __forceinline__ void split8(const float* x, short8& hi, short8& lo) {
  unsigned hb[8], lb[8];
#pragma unroll
  for (int e = 0; e < 8; e++) {
    unsigned xb = __float_as_uint(x[e]);
    unsigned h = xb & 0xFFFF0000u;
    float l = x[e] - __uint_as_float(h);    // exact
    hb[e] = h;
    lb[e] = __float_as_uint(l) & 0xFFFF0000u;
  }
  union U { unsigned u[4]; short8 s; };
  U H, L;
#pragma unroll
  for (int p = 0; p < 4; p++) {
    H.u[p] = __builtin_amdgcn_perm(hb[2 * p + 1], hb[2 * p], 0x07060302u);
    L.u[p] = __builtin_amdgcn_perm(lb[2 * p + 1], lb[2 * p], 0x07060302u);
  }
  hi = H.s;
  lo = L.s;
}

// ---------------------------------------------------------------------------
// prep bodies: weight -> MFMA B-fragment layout, split-bf16 hi/lo.
// W1F[kt(16)][NF(128)][hl(2)][lane(64)][e(8)]  (u/v row split baked in)
// W2F[kt(32)][nf(16)][hl(2)][lane(64)][e(8)]
// lane = 16g + c holds W[kt*32 + g*8 + e][NF*16 + c]  (same slot->k map as A).
// ---------------------------------------------------------------------------
__device__ __forceinline__ void prep_w1_body(
    int t, const float* __restrict__ W1, unsigned short* __restrict__ W1F) {
  int lane = t & 63;
  int nf = (t >> 6) & 127;
  int kt = t >> 13;                        // 0..15
  int g = lane >> 4, c = lane & 15;
  int n = nf * 16 + c;                     // 0..2047
  int kbase = kt * 32 + g * 8;
  const float* src = W1 + (long)((n >= 1024 ? 512 : 0) + kbase) * 1024 + (n & 1023);

  unsigned hb[8], lb[8];
#pragma unroll
  for (int e = 0; e < 8; e++) {
    float w = src[(long)e * 1024];
    unsigned wb = __float_as_uint(w);
    unsigned h = wb & 0xFFFF0000u;
    float l = w - __uint_as_float(h);
    hb[e] = h;
    lb[e] = __float_as_uint(l) & 0xFFFF0000u;
  }
  union U { unsigned u[4]; short8 s; };
  U H, L;
#pragma unroll
  for (int p = 0; p < 4; p++) {
    H.u[p] = __builtin_amdgcn_perm(hb[2 * p + 1], hb[2 * p], 0x07060302u);
    L.u[p] = __builtin_amdgcn_perm(lb[2 * p + 1], lb[2 * p], 0x07060302u);
  }
  long base = ((long)kt * 128 + nf) * 2 * 64 + lane;
  *(short8*)(W1F + (base + 0) * 8) = H.s;
  *(short8*)(W1F + (base + 64) * 8) = L.s;
}

__device__ __forceinline__ void prep_w2_body(
    int t, const float* __restrict__ W2, unsigned short* __restrict__ W2F) {
  int lane = t & 63;
  int nf = (t >> 6) & 15;
  int kt = t >> 10;                        // 0..31
  int g = lane >> 4, c = lane & 15;
  int n = nf * 16 + c;
  int kbase = kt * 32 + g * 8;

  unsigned hb[8], lb[8];
#pragma unroll
  for (int e = 0; e < 8; e++) {
    float w = W2[(long)(kbase + e) * 256 + n];
    unsigned wb = __float_as_uint(w);
    unsigned h = wb & 0xFFFF0000u;
    float l = w - __uint_as_float(h);
    hb[e] = h;
    lb[e] = __float_as_uint(l) & 0xFFFF0000u;
  }
  union U { unsigned u[4]; short8 s; };
  U H, L;
#pragma unroll
  for (int p = 0; p < 4; p++) {
    H.u[p] = __builtin_amdgcn_perm(hb[2 * p + 1], hb[2 * p], 0x07060302u);
    L.u[p] = __builtin_amdgcn_perm(lb[2 * p + 1], lb[2 * p], 0x07060302u);
  }
  long base = (((long)kt * 16 + nf) * 2) * 64 + lane;
  *(short8*)(W2F + (base + 0) * 8) = H.s;
  *(short8*)(W2F + (base + 64) * 8) = L.s;
}

// Fused prep: all 3 W1 (blocks 0..1535) + all 3 W2 (blocks 1536..1919).
__global__ __launch_bounds__(256) void prep_all(
    const float* __restrict__ Wf1, const float* __restrict__ Wh1a,
    const float* __restrict__ Wh2a, const float* __restrict__ Wf2,
    const float* __restrict__ Wh1b, const float* __restrict__ Wh2b,
    unsigned short* __restrict__ w1f_all, unsigned short* __restrict__ w2f_all) {
  int bx = blockIdx.x;
  if (bx < 1536) {
    int mlp = bx >> 9;
    const float* W1 = (mlp == 0) ? Wf1 : (mlp == 1) ? Wh1a : Wh2a;
    prep_w1_body((bx & 511) * 256 + threadIdx.x, W1,
                 w1f_all + (long)mlp * (2 * MB));   // 4 MiB = 2M shorts
  } else {
    int bb = bx - 1536;                             // 0..383
    int mlp = bb >> 7;
    const float* W2 = (mlp == 0) ? Wf2 : (mlp == 1) ? Wh1b : Wh2b;
    prep_w2_body((bb & 127) * 256 + threadIdx.x, W2,
                 w2f_all + (long)mlp * (MB / 2));   // 1 MiB = 512K shorts
  }
}

// Single-mlp prep wrappers (mid/low tiers).
__global__ __launch_bounds__(256) void prep_w1f(
    const float* __restrict__ W1, unsigned short* __restrict__ W1F) {
  prep_w1_body(blockIdx.x * 256 + threadIdx.x, W1, W1F);
}
__global__ __launch_bounds__(256) void prep_w2(
    const float* __restrict__ W2, unsigned short* __restrict__ W2F) {
  prep_w2_body(blockIdx.x * 256 + threadIdx.x, W2, W2F);
}

// ---------------------------------------------------------------------------
// stage1 core: uv[m][c'] = P[m] @ W1X[:, c'] via split-bf16 MFMA.
// bx in [0,512) = 32 mblk(16 rows) x 16 nblk(128 cols); 4 waves, 16m x 32n.
// ---------------------------------------------------------------------------
__device__ __forceinline__ void stage1_core(
    int bx, const float* __restrict__ P,
    const unsigned short* __restrict__ W1F, float* __restrict__ uv) {
  int m0 = (bx >> 4) * 16;
  int n0 = (bx & 15) * 128;
  int tid = threadIdx.x;
  int wid = tid >> 6, lane = tid & 63;
  int g = lane >> 4, r = lane & 15;
  int nw0 = n0 + wid * 32;                 // wave covers 2 n-frags

  const float* prow = P + (long)(m0 + r) * 512;

  floatx4 acc[2];
#pragma unroll
  for (int nf = 0; nf < 2; nf++) acc[nf] = (floatx4){0.f, 0.f, 0.f, 0.f};

  for (int kt = 0; kt < 16; kt++) {
    int k0 = kt * 32 + g * 8;
    float a[8];
    floatx4 a0 = *(const floatx4*)(prow + k0);
    floatx4 a1 = *(const floatx4*)(prow + k0 + 4);
#pragma unroll
    for (int e = 0; e < 4; e++) { a[e] = a0[e]; a[4 + e] = a1[e]; }
    short8 ahi, alo;
    split8(a, ahi, alo);
#pragma unroll
    for (int nf = 0; nf < 2; nf++) {
      int nfg = (nw0 >> 4) + nf;
      const unsigned short* wp = W1F + (((long)kt * 128 + nfg) * 2 * 64 + lane) * 8;
      short8 whi = *(const short8*)wp;
      short8 wlo = *(const short8*)(wp + 64 * 8);
      acc[nf] = __builtin_amdgcn_mfma_f32_16x16x32_bf16(ahi, whi, acc[nf], 0, 0, 0);
      acc[nf] = __builtin_amdgcn_mfma_f32_16x16x32_bf16(alo, whi, acc[nf], 0, 0, 0);
      acc[nf] = __builtin_amdgcn_mfma_f32_16x16x32_bf16(ahi, wlo, acc[nf], 0, 0, 0);
    }
  }
  // D: row = g*4 + reg (m), col = r (n)
#pragma unroll
  for (int nf = 0; nf < 2; nf++)
#pragma unroll
    for (int reg = 0; reg < 4; reg++)
      uv[(long)(m0 + g * 4 + reg) * 2048 + nw0 + nf * 16 + r] = acc[nf][reg];
}

__global__ __launch_bounds__(256) void stage1_mfma(
    const float* __restrict__ P, const unsigned short* __restrict__ W1F,
    float* __restrict__ uv) {
  stage1_core(blockIdx.x, P, W1F, uv);
}

__global__ __launch_bounds__(256) void stage1_mfma3(
    const float* __restrict__ P, const unsigned short* __restrict__ w1f_all,
    float* __restrict__ uv_all) {
  int mlp = blockIdx.x >> 9;
  stage1_core(blockIdx.x & 511, P, w1f_all + (long)mlp * (2 * MB),
              uv_all + (long)mlp * MB);    // 4 MiB = 1M floats
}

// ---------------------------------------------------------------------------
// pair core: split-bf16 3-product MFMA, LDS-staged B (2x32KB dbuf), fused
// head. 512 thr = 8 waves; wave (jh = wid>>2, nq = wid&3) owns 64 j x 64 n.
// acc[4][4] = 64 regs; each B frag read feeds 4 m-frags (halved ds_reads).
// ---------------------------------------------------------------------------
__device__ __forceinline__ void pair_core(
    int bi, const float* __restrict__ uv,
    const unsigned short* __restrict__ W2F, const float* __restrict__ w3,
    float* __restrict__ out, int mlp, unsigned short (*wbuf)[16384]) {
  int b = bi >> 7;
  int tid = threadIdx.x;
  int wid = tid >> 6;           // 0..7
  int lane = tid & 63;
  int jh = wid >> 2;            // j-half: rows [jh*64, +64)
  int nq = wid & 3;             // n-quarter: cols [nq*64, +64)
  int g = lane >> 4;
  int r = lane & 15;
  int wj = jh * 64;

  const float* ubase = uv + (long)bi * 2048;
  const float* vbase = uv + (long)(b * 128 + wj + r) * 2048 + 1024;

  floatx4 acc[4][4];
#pragma unroll
  for (int mm = 0; mm < 4; mm++)
#pragma unroll
    for (int nf = 0; nf < 4; nf++) acc[mm][nf] = (floatx4){0.f, 0.f, 0.f, 0.f};

  // Prologue: stage kt=0 slice (32 KB; 4 x 16B chunks per thread).
#pragma unroll
  for (int i = 0; i < 4; i++)
    gload_lds16(W2F + (i * 512 + tid) * 8, &wbuf[0][(i * 512 + tid) * 8]);
  __syncthreads();   // drains vmcnt(0): slice 0 resident

  int cur = 0;
  for (int kt = 0; kt < 32; kt++) {
    // Issue next-slice prefetch FIRST (flies under this tile's compute).
    if (kt < 31) {
      const unsigned short* gs = W2F + (long)(kt + 1) * 16384;
#pragma unroll
      for (int i = 0; i < 4; i++)
        gload_lds16(gs + (i * 512 + tid) * 8, &wbuf[cur ^ 1][(i * 512 + tid) * 8]);
    }

    int k0 = kt * 32 + g * 8;
    floatx4 u0 = *(const floatx4*)(ubase + k0);
    floatx4 u1 = *(const floatx4*)(ubase + k0 + 4);
    short8 ahi[4], alo[4];
#pragma unroll
    for (int mm = 0; mm < 4; mm++) {
      const float* vr = vbase + (long)mm * 16 * 2048;
      floatx4 va = *(const floatx4*)(vr + k0);
      floatx4 vb = *(const floatx4*)(vr + k0 + 4);
      float z[8];
#pragma unroll
      for (int e = 0; e < 4; e++) {
        z[e]     = fmaxf(u0[e] + va[e], 0.f);
        z[4 + e] = fmaxf(u1[e] + vb[e], 0.f);
      }
      split8(z, ahi[mm], alo[mm]);
    }

    __builtin_amdgcn_s_setprio(1);
#pragma unroll
    for (int nf = 0; nf < 4; nf++) {
      const unsigned short* wp = &wbuf[cur][((nq * 4 + nf) * 2) * 512 + lane * 8];
      short8 whi = *(const short8*)wp;
      short8 wlo = *(const short8*)(wp + 512);
#pragma unroll
      for (int mm = 0; mm < 4; mm++) {
        acc[mm][nf] = __builtin_amdgcn_mfma_f32_16x16x32_bf16(
            ahi[mm], whi, acc[mm][nf], 0, 0, 0);
        acc[mm][nf] = __builtin_amdgcn_mfma_f32_16x16x32_bf16(
            alo[mm], whi, acc[mm][nf], 0, 0, 0);
        acc[mm][nf] = __builtin_amdgcn_mfma_f32_16x16x32_bf16(
            ahi[mm], wlo, acc[mm][nf], 0, 0, 0);
      }
    }
    __builtin_amdgcn_s_setprio(0);
    __syncthreads();   // next slice resident + this buffer's reads drained
    cur ^= 1;
  }

  // Epilogue: D col = r (n within frag), row = g*4 + reg (j within m-frag).
  // y stores + per-nq head partials; partials combined via LDS scratch.
  float* ps = (float*)wbuf;   // psum[row(128)][nq(4)][c(2)] floats = 4 KB
  float* ob = out + (long)(bi * 128) * 774 + mlp * 258;
  floatx2 w3v[4];
#pragma unroll
  for (int nf = 0; nf < 4; nf++)
    w3v[nf] = *(const floatx2*)(w3 + ((nq * 4 + nf) * 16 + r) * 2);
#pragma unroll
  for (int mm = 0; mm < 4; mm++) {
#pragma unroll
    for (int reg = 0; reg < 4; reg++) {
      int row = wj + mm * 16 + g * 4 + reg;
      float* orow = ob + (long)row * 774 + nq * 64;
      float s0 = 0.f, s1 = 0.f;
#pragma unroll
      for (int nf = 0; nf < 4; nf++) {
        float y = acc[mm][nf][reg];
        y = y > 0.f ? y : 0.f;
        orow[nf * 16 + r] = y;
        s0 += y * w3v[nf][0];
        s1 += y * w3v[nf][1];
      }
#pragma unroll
      for (int off = 1; off < 16; off <<= 1) {
        s0 += __shfl_xor(s0, off, 64);
        s1 += __shfl_xor(s1, off, 64);
      }
      if (r == 0) {
        ps[row * 8 + nq * 2 + 0] = s0;
        ps[row * 8 + nq * 2 + 1] = s1;
      }
    }
  }
  __syncthreads();
  if (tid < 128) {
    int row = tid;
    float s0 = ps[row * 8 + 0] + ps[row * 8 + 2] + ps[row * 8 + 4] + ps[row * 8 + 6];
    float s1 = ps[row * 8 + 1] + ps[row * 8 + 3] + ps[row * 8 + 5] + ps[row * 8 + 7];
    float m = fmaxf(s0, s1);
    float e0 = __expf(s0 - m), e1 = __expf(s1 - m);
    float inv = 1.0f / (e0 + e1);
    floatx2 pr;
    pr[0] = e0 * inv;
    pr[1] = e1 * inv;
    *(floatx2*)(ob + (long)row * 774 + 256) = pr;   // 8B aligned
  }
}

__global__ __launch_bounds__(512, 4) void pair_mfma(
    const float* __restrict__ uv, const unsigned short* __restrict__ W2F,
    const float* __restrict__ w3, float* __restrict__ out, int mlp) {
  __shared__ unsigned short wbuf[2][16384];
  pair_core(blockIdx.x, uv, W2F, w3, out, mlp, wbuf);
}

__global__ __launch_bounds__(512, 4) void pair_mfma3(
    const float* __restrict__ uv_all, const unsigned short* __restrict__ w2f_all,
    const float* __restrict__ w3_0, const float* __restrict__ w3_1,
    const float* __restrict__ w3_2, float* __restrict__ out) {
  __shared__ unsigned short wbuf[2][16384];
  int mlp = blockIdx.x >> 9;
  const float* w3 = (mlp == 0) ? w3_0 : (mlp == 1) ? w3_1 : w3_2;
  pair_core(blockIdx.x & 511, uv_all + (long)mlp * MB,
            w2f_all + (long)mlp * (MB / 2), w3, out, mlp, wbuf);
}

// ---------------------------------------------------------------------------
// VALU fallbacks (proven; used only on small workspaces).
// ---------------------------------------------------------------------------
__global__ __launch_bounds__(256) void stage1_valu(
    const float* __restrict__ P, const float* __restrict__ W1,
    float* __restrict__ uv) {
  __shared__ float at[KT][LSTRIDE];
  __shared__ float wt[KT][LSTRIDE];
  int bx = blockIdx.x;
  int m0 = (bx >> 5) * 64;
  int c0 = (bx & 31) * 64;
  int half = c0 >> 10;
  int ccol = c0 & 1023;
  int tid = threadIdx.x;
  int tm = tid >> 4, tn = tid & 15;
  int lm = tid >> 2;
  int lk4 = (tid & 3) * 4;
  int lkk = tid >> 4;
  int lc4 = (tid & 15) * 4;

  float acc[4][4] = {};

  for (int k0 = 0; k0 < 512; k0 += KT) {
    floatx4 pa = *(const floatx4*)(P + (long)(m0 + lm) * 512 + k0 + lk4);
    floatx4 wa = *(const floatx4*)(W1 + (long)(half * 512 + k0 + lkk) * 1024 + ccol + lc4);
    __syncthreads();
#pragma unroll
    for (int e = 0; e < 4; e++) at[lk4 + e][lm] = pa[e];
    *(floatx4*)&wt[lkk][lc4] = wa;
    __syncthreads();
#pragma unroll
    for (int kk = 0; kk < KT; kk++) {
      floatx4 av = *(const floatx4*)&at[kk][tm * 4];
      floatx4 wv = *(const floatx4*)&wt[kk][tn * 4];
#pragma unroll
      for (int mm = 0; mm < 4; mm++)
#pragma unroll
        for (int nn = 0; nn < 4; nn++)
          acc[mm][nn] += av[mm] * wv[nn];
    }
  }
#pragma unroll
  for (int mm = 0; mm < 4; mm++) {
    floatx4 o;
#pragma unroll
    for (int nn = 0; nn < 4; nn++) o[nn] = acc[mm][nn];
    *(floatx4*)(uv + (long)(m0 + tm * 4 + mm) * 2048 + c0 + tn * 4) = o;
  }
}

__global__ __launch_bounds__(256) void pair_valu(
    const float* __restrict__ uv, const float* __restrict__ W2,
    float* __restrict__ out, int mlp) {
  __shared__ float zt[KT][LSTRIDE];
  __shared__ float wt[KT][LSTRIDE];
  int bx = blockIdx.x;               // 4096 = 512 bi x 2 jh x 4 nb
  int nb = bx & 3;
  int jh = (bx >> 2) & 1;
  int bi = bx >> 3;
  int b = bi >> 7;
  int j0 = jh * 64;
  int n0 = nb * 64;
  int tid = threadIdx.x;
  int tm = tid >> 4, tn = tid & 15;
  int lj = tid >> 2;
  int lk4 = (tid & 3) * 4;
  int lkk = tid >> 4;
  int ln4 = (tid & 15) * 4;

  const float* urow = uv + (long)bi * 2048;
  const float* vrow = uv + (long)(b * 128 + j0 + lj) * 2048 + 1024;

  float acc[4][4] = {};

  for (int k0 = 0; k0 < 1024; k0 += KT) {
    floatx4 uu = *(const floatx4*)(urow + k0 + lk4);
    floatx4 vv = *(const floatx4*)(vrow + k0 + lk4);
    floatx4 wa = *(const floatx4*)(W2 + (long)(k0 + lkk) * 256 + n0 + ln4);
    __syncthreads();
#pragma unroll
    for (int e = 0; e < 4; e++) {
      float z = uu[e] + vv[e];
      zt[lk4 + e][lj] = z > 0.f ? z : 0.f;
    }
    *(floatx4*)&wt[lkk][ln4] = wa;
    __syncthreads();
#pragma unroll
    for (int kk = 0; kk < KT; kk++) {
      floatx4 zv = *(const floatx4*)&zt[kk][tm * 4];
      floatx4 wv = *(const floatx4*)&wt[kk][tn * 4];
#pragma unroll
      for (int mm = 0; mm < 4; mm++)
#pragma unroll
        for (int nn = 0; nn < 4; nn++)
          acc[mm][nn] += zv[mm] * wv[nn];
    }
  }
  float* ob = out + (long)(bi * 128 + j0) * 774 + mlp * 258 + n0 + tn * 4;
#pragma unroll
  for (int mm = 0; mm < 4; mm++) {
    float* orow = ob + (long)(tm * 4 + mm) * 774;
    floatx2 pa, pb;
    pa[0] = acc[mm][0] > 0.f ? acc[mm][0] : 0.f;
    pa[1] = acc[mm][1] > 0.f ? acc[mm][1] : 0.f;
    pb[0] = acc[mm][2] > 0.f ? acc[mm][2] : 0.f;
    pb[1] = acc[mm][3] > 0.f ? acc[mm][3] : 0.f;
    *(floatx2*)orow = pa;
    *(floatx2*)(orow + 2) = pb;
  }
}

__global__ __launch_bounds__(256) void head_kernel(
    const float* __restrict__ w3_0, const float* __restrict__ w3_1,
    const float* __restrict__ w3_2, float* out) {
  int wid = threadIdx.x >> 6, lane = threadIdx.x & 63;
  int r = blockIdx.x * 4 + wid;   // [0, 196608)
  int mlp = r >> 16;
  int row = r & 65535;
  const float* w3 = (mlp == 0) ? w3_0 : (mlp == 1) ? w3_1 : w3_2;
  const float* yp = out + (long)row * 774 + mlp * 258 + lane * 4;
  floatx2 ya = *(const floatx2*)yp;
  floatx2 yb = *(const floatx2*)(yp + 2);
  const float* wp = w3 + lane * 8;
  floatx4 wv0 = *(const floatx4*)wp;
  floatx4 wv1 = *(const floatx4*)(wp + 4);
  float s0 = ya[0] * wv0[0] + ya[1] * wv0[2] + yb[0] * wv1[0] + yb[1] * wv1[2];
  float s1 = ya[0] * wv0[1] + ya[1] * wv0[3] + yb[0] * wv1[1] + yb[1] * wv1[3];
#pragma unroll
  for (int off = 32; off > 0; off >>= 1) {
    s0 += __shfl_xor(s0, off, 64);
    s1 += __shfl_xor(s1, off, 64);
  }
  if (lane == 0) {
    float m = fmaxf(s0, s1);
    float e0 = __expf(s0 - m), e1 = __expf(s1 - m);
    float inv = 1.0f / (e0 + e1);
    floatx2 pr;
    pr[0] = e0 * inv;
    pr[1] = e1 * inv;
    *(floatx2*)(out + (long)row * 774 + mlp * 258 + 256) = pr;
  }
}

extern "C" void kernel_launch(void* const* d_in, const int* in_sizes, int n_in,
                              void* d_out, int out_size, void* d_ws, size_t ws_size,
                              hipStream_t stream) {
  const float* para = (const float*)d_in[0];
  const float* Wf1  = (const float*)d_in[1];
  const float* Wf2  = (const float*)d_in[2];
  const float* w3   = (const float*)d_in[3];
  const float* Wh1a = (const float*)d_in[4];
  const float* Wh1b = (const float*)d_in[5];
  const float* wl1  = (const float*)d_in[6];
  const float* Wh2a = (const float*)d_in[7];
  const float* Wh2b = (const float*)d_in[8];
  const float* wl2  = (const float*)d_in[9];

  float* outp = (float*)d_out;   // f32 [4*128*128][774]

  const float* W1s[3] = {Wf1, Wh1a, Wh2a};
  const float* W2s[3] = {Wf2, Wh1b, Wh2b};
  const float* w3s[3] = {w3, wl1, wl2};

  if (ws_size >= (size_t)27 * MB) {
    // Fused tier: 3 launches total.
    float* uv_all = (float*)d_ws;                                    // 12 MiB
    unsigned short* w2f_all = (unsigned short*)((char*)d_ws + 12 * MB); // 3 MiB
    unsigned short* w1f_all = (unsigned short*)((char*)d_ws + 15 * MB); // 12 MiB
    prep_all<<<1920, 256, 0, stream>>>(Wf1, Wh1a, Wh2a, Wf2, Wh1b, Wh2b,
                                       w1f_all, w2f_all);
    stage1_mfma3<<<1536, 256, 0, stream>>>(para, w1f_all, uv_all);
    pair_mfma3<<<1536, 512, 0, stream>>>(uv_all, w2f_all, w3, wl1, wl2, outp);
  } else if (ws_size >= (size_t)9 * MB) {
    float* uv = (float*)d_ws;
    unsigned short* w2f = (unsigned short*)((char*)d_ws + 4 * MB);
    unsigned short* w1f = (unsigned short*)((char*)d_ws + 5 * MB);
    for (int mlp = 0; mlp < 3; mlp++) {
      prep_w1f<<<512, 256, 0, stream>>>(W1s[mlp], w1f);
      stage1_mfma<<<512, 256, 0, stream>>>(para, w1f, uv);
      prep_w2<<<128, 256, 0, stream>>>(W2s[mlp], w2f);
      pair_mfma<<<512, 512, 0, stream>>>(uv, w2f, w3s[mlp], outp, mlp);
    }
  } else if (ws_size >= (size_t)5 * MB) {
    float* uv = (float*)d_ws;
    unsigned short* w2f = (unsigned short*)((char*)d_ws + 4 * MB);
    for (int mlp = 0; mlp < 3; mlp++) {
      stage1_valu<<<256, 256, 0, stream>>>(para, W1s[mlp], uv);
      prep_w2<<<128, 256, 0, stream>>>(W2s[mlp], w2f);
      pair_mfma<<<512, 512, 0, stream>>>(uv, w2f, w3s[mlp], outp, mlp);
    }
  } else {
    float* uv = (float*)d_ws;
    for (int mlp = 0; mlp < 3; mlp++) {
      stage1_valu<<<256, 256, 0, stream>>>(para, W1s[mlp], uv);
      pair_valu<<<4096, 256, 0, stream>>>(uv, W2s[mlp], outp, mlp);
    }
    head_kernel<<<49152, 256, 0, stream>>>(w3, wl1, wl2, outp);
  }
}

// Round 5
// 473.630 us; speedup vs baseline: 1.5314x; 1.5314x over previous
//
#include <hip/hip_runtime.h>

// PointerNet: B=4, N=128, H=512, d_pair=256.
// Interface (verified):
//   inputs  f32, setup_inputs dict order
//   d_out   f32, 50,724,864 elements = [4][128][128][774]
// Per mlp g in {future(Wf1,Wf2,w3), hist1(Wh1a,Wh1b,wl1), hist2(Wh2a,Wh2b,wl2)}:
//   uv[m][c'] = sum_h P[m][h] * W1[(c'>=1024?512:0)+h][c'&1023]     (m = b*128+i)
//   y[bi,j,n] = relu( sum_k relu(u[bi][k] + v[bj][k]) * W2[k][n] )
//   p = softmax_c( sum_n y[n] * w3[n][c] )
//   out[((bi)*128+j)*774 + g*258 + {n | 256+c}] = {y | p}
//
// R13 changes (post-mortem of R12 regression 545->725):
//   * pair wave shape back to redundancy-2 (4 j-quarters x 2 n-halves); R12's
//     2x4 split doubled z-recompute VALU (VALUBusy 35 > MfmaUtil 24).
//   * v stored in MFMA-fragment-major layout vF by stage1 -> pair A-frag load
//     is ONE coalesced 2KB load (base + lane*8) instead of 16-segment scatter
//     (the real wall since R1). u stays row-major (broadcast, L1-hot).
//   * register prefetch of kt+1 A-frags under the MFMA cluster.
//   * XCD-aware bijective swizzle on the 1536-block pair grid (1536 = 8*192).
//
// Workspace (fused tier, ws>=27MiB):
//   uF_all  f32 [3][512][1024]   6 MiB @0     (u half, row-major)
//   vF_all  f32 [3][524288]      6 MiB @6M    (v half, fragment-major)
//   w2f_all u16 [3][524288]      3 MiB @12M
//   w1f_all u16 [3][2M]         12 MiB @15M
// Fallback (<27MiB): all-VALU path (uv row-major 4 MiB @0) + head_kernel.

typedef __attribute__((ext_vector_type(4))) float floatx4;
typedef __attribute__((ext_vector_type(2))) float floatx2;
typedef __attribute__((ext_vector_type(8))) short short8;

#define KT 16
#define LSTRIDE 68  // 64 + 4 pad (LDS bank-conflict break)
#define MB (1u << 20)

__device__ __forceinline__ void gload_lds16(const void* g, void* l) {
  __builtin_amdgcn_global_load_lds(
      (const __attribute__((address_space(1))) void*)g,
      (__attribute__((address_space(3))) void*)l, 16, 0, 0);
}

// Split 8 f32 into bf16 hi (truncated) + bf16 lo (exact remainder, truncated).
__device__ __forceinline__ void split8(const float* x, short8& hi, short8& lo) {
  unsigned hb[8], lb[8];
#pragma unroll
  for (int e = 0; e < 8; e++) {
    unsigned xb = __float_as_uint(x[e]);
    unsigned h = xb & 0xFFFF0000u;
    float l = x[e] - __uint_as_float(h);    // exact
    hb[e] = h;
    lb[e] = __float_as_uint(l) & 0xFFFF0000u;
  }
  union U { unsigned u[4]; short8 s; };
  U H, L;
#pragma unroll
  for (int p = 0; p < 4; p++) {
    H.u[p] = __builtin_amdgcn_perm(hb[2 * p + 1], hb[2 * p], 0x07060302u);
    L.u[p] = __builtin_amdgcn_perm(lb[2 * p + 1], lb[2 * p], 0x07060302u);
  }
  hi = H.s;
  lo = L.s;
}

// z = relu(u + v) for 8 k-slots, then split-bf16.
__device__ __forceinline__ void make_frag(
    const floatx4& ua, const floatx4& ub,
    const floatx4& va, const floatx4& vb,
    short8& hi, short8& lo) {
  float z[8];
#pragma unroll
  for (int e = 0; e < 4; e++) {
    z[e] = fmaxf(ua[e] + va[e], 0.0f);
    z[4 + e] = fmaxf(ub[e] + vb[e], 0.0f);
  }
  split8(z, hi, lo);
}

// ---------------------------------------------------------------------------
// prep bodies: weight -> MFMA B-fragment layout, split-bf16 hi/lo.
// W1F[kt(16)][NF(128)][hl(2)][lane(64)][e(8)]  (u/v row split baked in)
// W2F[kt(32)][nf(16)][hl(2)][lane(64)][e(8)]
// lane = 16g + c holds W[kt*32 + g*8 + e][NF*16 + c]  (same slot->k map as A).
// ---------------------------------------------------------------------------
__device__ __forceinline__ void prep_w1_body(
    int t, const float* __restrict__ W1, unsigned short* __restrict__ W1F) {
  int lane = t & 63;
  int nf = (t >> 6) & 127;
  int kt = t >> 13;                        // 0..15
  int g = lane >> 4, c = lane & 15;
  int n = nf * 16 + c;                     // 0..2047
  int kbase = kt * 32 + g * 8;
  const float* src = W1 + (long)((n >= 1024 ? 512 : 0) + kbase) * 1024 + (n & 1023);

  unsigned hb[8], lb[8];
#pragma unroll
  for (int e = 0; e < 8; e++) {
    float w = src[(long)e * 1024];
    unsigned wb = __float_as_uint(w);
    unsigned h = wb & 0xFFFF0000u;
    float l = w - __uint_as_float(h);
    hb[e] = h;
    lb[e] = __float_as_uint(l) & 0xFFFF0000u;
  }
  union U { unsigned u[4]; short8 s; };
  U H, L;
#pragma unroll
  for (int p = 0; p < 4; p++) {
    H.u[p] = __builtin_amdgcn_perm(hb[2 * p + 1], hb[2 * p], 0x07060302u);
    L.u[p] = __builtin_amdgcn_perm(lb[2 * p + 1], lb[2 * p], 0x07060302u);
  }
  long base = ((long)kt * 128 + nf) * 2 * 64 + lane;
  *(short8*)(W1F + (base + 0) * 8) = H.s;
  *(short8*)(W1F + (base + 64) * 8) = L.s;
}

__device__ __forceinline__ void prep_w2_body(
    int t, const float* __restrict__ W2, unsigned short* __restrict__ W2F) {
  int lane = t & 63;
  int nf = (t >> 6) & 15;
  int kt = t >> 10;                        // 0..31
  int g = lane >> 4, c = lane & 15;
  int n = nf * 16 + c;
  int kbase = kt * 32 + g * 8;

  unsigned hb[8], lb[8];
#pragma unroll
  for (int e = 0; e < 8; e++) {
    float w = W2[(long)(kbase + e) * 256 + n];
    unsigned wb = __float_as_uint(w);
    unsigned h = wb & 0xFFFF0000u;
    float l = w - __uint_as_float(h);
    hb[e] = h;
    lb[e] = __float_as_uint(l) & 0xFFFF0000u;
  }
  union U { unsigned u[4]; short8 s; };
  U H, L;
#pragma unroll
  for (int p = 0; p < 4; p++) {
    H.u[p] = __builtin_amdgcn_perm(hb[2 * p + 1], hb[2 * p], 0x07060302u);
    L.u[p] = __builtin_amdgcn_perm(lb[2 * p + 1], lb[2 * p], 0x07060302u);
  }
  long base = (((long)kt * 16 + nf) * 2) * 64 + lane;
  *(short8*)(W2F + (base + 0) * 8) = H.s;
  *(short8*)(W2F + (base + 64) * 8) = L.s;
}

// Fused prep: all 3 W1 (blocks 0..1535) + all 3 W2 (blocks 1536..1919).
__global__ __launch_bounds__(256) void prep_all(
    const float* __restrict__ Wf1, const float* __restrict__ Wh1a,
    const float* __restrict__ Wh2a, const float* __restrict__ Wf2,
    const float* __restrict__ Wh1b, const float* __restrict__ Wh2b,
    unsigned short* __restrict__ w1f_all, unsigned short* __restrict__ w2f_all) {
  int bx = blockIdx.x;
  if (bx < 1536) {
    int mlp = bx >> 9;
    const float* W1 = (mlp == 0) ? Wf1 : (mlp == 1) ? Wh1a : Wh2a;
    prep_w1_body((bx & 511) * 256 + threadIdx.x, W1,
                 w1f_all + (long)mlp * (2 * MB));   // 4 MiB = 2M shorts
  } else {
    int bb = bx - 1536;                             // 0..383
    int mlp = bb >> 7;
    const float* W2 = (mlp == 0) ? Wf2 : (mlp == 1) ? Wh1b : Wh2b;
    prep_w2_body((bb & 127) * 256 + threadIdx.x, W2,
                 w2f_all + (long)mlp * (MB / 2));   // 1 MiB = 512K shorts
  }
}

// ---------------------------------------------------------------------------
// stage1 core: split-bf16 MFMA, writes uF (row-major) or vF (fragment-major).
// bx in [0,512) = 32 mblk(16 rows) x 16 nblk(128 cols); 4 waves, 16m x 32n.
// vF flat index: (((b*32 + kt)*8 + jf)*4 + g)*128 + r*8 + e
//   holds v[b*128 + jf*16 + r][kt*32 + g*8 + e].
// ---------------------------------------------------------------------------
__device__ __forceinline__ void stage1_core(
    int bx, const float* __restrict__ P,
    const unsigned short* __restrict__ W1F,
    float* __restrict__ uF, float* __restrict__ vF) {
  int m0 = (bx >> 4) * 16;
  int n0 = (bx & 15) * 128;
  int tid = threadIdx.x;
  int wid = tid >> 6, lane = tid & 63;
  int g = lane >> 4, r = lane & 15;
  int nw0 = n0 + wid * 32;                 // wave covers 2 n-frags

  const float* prow = P + (long)(m0 + r) * 512;

  floatx4 acc[2];
#pragma unroll
  for (int nf = 0; nf < 2; nf++) acc[nf] = (floatx4){0.f, 0.f, 0.f, 0.f};

  for (int kt = 0; kt < 16; kt++) {
    int k0 = kt * 32 + g * 8;
    float a[8];
    floatx4 a0 = *(const floatx4*)(prow + k0);
    floatx4 a1 = *(const floatx4*)(prow + k0 + 4);
#pragma unroll
    for (int e = 0; e < 4; e++) { a[e] = a0[e]; a[4 + e] = a1[e]; }
    short8 ahi, alo;
    split8(a, ahi, alo);
#pragma unroll
    for (int nf = 0; nf < 2; nf++) {
      int nfg = (nw0 >> 4) + nf;
      const unsigned short* wp = W1F + (((long)kt * 128 + nfg) * 2 * 64 + lane) * 8;
      short8 whi = *(const short8*)wp;
      short8 wlo = *(const short8*)(wp + 64 * 8);
      acc[nf] = __builtin_amdgcn_mfma_f32_16x16x32_bf16(ahi, whi, acc[nf], 0, 0, 0);
      acc[nf] = __builtin_amdgcn_mfma_f32_16x16x32_bf16(alo, whi, acc[nf], 0, 0, 0);
      acc[nf] = __builtin_amdgcn_mfma_f32_16x16x32_bf16(ahi, wlo, acc[nf], 0, 0, 0);
    }
  }
  // D: row = g*4 + reg (m within 16-tile), col = r (n within nf 16-tile)
  if (n0 < 1024) {
    // u half -> row-major uF[m][k], k = col index
#pragma unroll
    for (int nf = 0; nf < 2; nf++)
#pragma unroll
      for (int reg = 0; reg < 4; reg++)
        uF[(long)(m0 + g * 4 + reg) * 1024 + nw0 + nf * 16 + r] = acc[nf][reg];
  } else {
    // v half -> fragment-major vF
    int kt = (nw0 - 1024) >> 5;            // wave-uniform
    long base = ((long)((m0 >> 7) * 32 + kt) * 8 + ((m0 >> 4) & 7)) * 512;
#pragma unroll
    for (int nf = 0; nf < 2; nf++) {
      int gt = nf * 2 + (r >> 3);
#pragma unroll
      for (int reg = 0; reg < 4; reg++)
        vF[base + (gt * 16 + g * 4 + reg) * 8 + (r & 7)] = acc[nf][reg];
    }
  }
}

__global__ __launch_bounds__(256) void stage1_mfma3(
    const float* __restrict__ P, const unsigned short* __restrict__ w1f_all,
    float* __restrict__ uF_all, float* __restrict__ vF_all) {
  int mlp = blockIdx.x >> 9;
  stage1_core(blockIdx.x & 511, P, w1f_all + (long)mlp * (2 * MB),
              uF_all + (long)mlp * 524288, vF_all + (long)mlp * 524288);
}

// ---------------------------------------------------------------------------
// pair kernel: split-bf16 3-product MFMA. 512 thr = 8 waves; wave (jq =
// wid>>1: 32 j rows, nh = wid&1: 128 n cols) -> redundancy-2 z compute.
// A-frags: coalesced vF loads (base + lane*8), reg-prefetched one kt ahead.
// B: LDS double-buffered W2F slices (32 KB) via global_load_lds.
// Head fused via LDS psum. acc[2][8] = 64 VGPR.
// ---------------------------------------------------------------------------
__global__ __launch_bounds__(512, 4) void pair_mfma3(
    const float* __restrict__ uF_all, const float* __restrict__ vF_all,
    const unsigned short* __restrict__ w2f_all,
    const float* __restrict__ w3_0, const float* __restrict__ w3_1,
    const float* __restrict__ w3_2, float* __restrict__ out) {
  __shared__ unsigned short wbuf[2][16384];   // 2 x 32 KB
  int orig = blockIdx.x;                      // 1536 = 8 XCD * 192
  int id = (orig & 7) * 192 + (orig >> 3);    // bijective XCD swizzle
  int mlp = id >> 9;
  int bi = id & 511;
  int b = bi >> 7;
  const float* w3 = (mlp == 0) ? w3_0 : (mlp == 1) ? w3_1 : w3_2;
  const float* uF = uF_all + (long)mlp * 524288;
  const float* vF = vF_all + (long)mlp * 524288;
  const unsigned short* W2F = w2f_all + (long)mlp * 524288;

  int tid = threadIdx.x;
  int wid = tid >> 6;           // 0..7
  int lane = tid & 63;
  int jq = wid >> 1;            // j-quarter: rows [jq*32, +32)
  int nh = wid & 1;             // n-half: cols [nh*128, +128)
  int g = lane >> 4;
  int r = lane & 15;

  const float* urow = uF + (long)bi * 1024;
  // vF base for (b, kt, jf): ((b*32+kt)*8 + jf)*512 + lane*8
  long vb0 = ((long)b * 32 * 8 + (jq * 2 + 0)) * 512 + lane * 8;
  long vb1 = ((long)b * 32 * 8 + (jq * 2 + 1)) * 512 + lane * 8;

  floatx4 acc[2][8];
#pragma unroll
  for (int mm = 0; mm < 2; mm++)
#pragma unroll
    for (int nf = 0; nf < 8; nf++) acc[mm][nf] = (floatx4){0.f, 0.f, 0.f, 0.f};

  // Prologue: stage B slice kt=0; load A data kt=0.
#pragma unroll
  for (int i = 0; i < 4; i++)
    gload_lds16(W2F + (i * 512 + tid) * 8, &wbuf[0][(i * 512 + tid) * 8]);
  floatx4 u0c = *(const floatx4*)(urow + g * 8);
  floatx4 u1c = *(const floatx4*)(urow + g * 8 + 4);
  floatx4 va0c[2], va1c[2];
  va0c[0] = *(const floatx4*)(vF + vb0);
  va1c[0] = *(const floatx4*)(vF + vb0 + 4);
  va0c[1] = *(const floatx4*)(vF + vb1);
  va1c[1] = *(const floatx4*)(vF + vb1 + 4);
  __syncthreads();   // drains vmcnt(0): B slice 0 + A regs resident

  int cur = 0;
  for (int kt = 0; kt < 32; kt++) {
    // Issue next B-slice prefetch FIRST (flies under this tile's compute).
    if (kt < 31) {
      const unsigned short* gs = W2F + (long)(kt + 1) * 16384;
#pragma unroll
      for (int i = 0; i < 4; i++)
        gload_lds16(gs + (i * 512 + tid) * 8, &wbuf[cur ^ 1][(i * 512 + tid) * 8]);
    }

    // Build A fragments for this kt from prefetched regs.
    short8 ahi[2], alo[2];
    make_frag(u0c, u1c, va0c[0], va1c[0], ahi[0], alo[0]);
    make_frag(u0c, u1c, va0c[1], va1c[1], ahi[1], alo[1]);

    // Prefetch A for kt+1 (hides L2 latency under the MFMA cluster).
    if (kt < 31) {
      int k0 = (kt + 1) * 32 + g * 8;
      long vo = (long)(kt + 1) * 8 * 512;
      u0c = *(const floatx4*)(urow + k0);
      u1c = *(const floatx4*)(urow + k0 + 4);
      va0c[0] = *(const floatx4*)(vF + vb0 + vo);
      va1c[0] = *(const floatx4*)(vF + vb0 + vo + 4);
      va0c[1] = *(const floatx4*)(vF + vb1 + vo);
      va1c[1] = *(const floatx4*)(vF + vb1 + vo + 4);
    }

    __builtin_amdgcn_s_setprio(1);
#pragma unroll
    for (int nf = 0; nf < 8; nf++) {
      const unsigned short* wp = &wbuf[cur][((nh * 8 + nf) * 2) * 512 + lane * 8];
      short8 whi = *(const short8*)wp;
      short8 wlo = *(const short8*)(wp + 512);
#pragma unroll
      for (int mm = 0; mm < 2; mm++) {
        acc[mm][nf] = __builtin_amdgcn_mfma_f32_16x16x32_bf16(
            ahi[mm], whi, acc[mm][nf], 0, 0, 0);
        acc[mm][nf] = __builtin_amdgcn_mfma_f32_16x16x32_bf16(
            alo[mm], whi, acc[mm][nf], 0, 0, 0);
        acc[mm][nf] = __builtin_amdgcn_mfma_f32_16x16x32_bf16(
            ahi[mm], wlo, acc[mm][nf], 0, 0, 0);
      }
    }
    __builtin_amdgcn_s_setprio(0);
    __syncthreads();   // next B slice resident + this buffer's reads drained
    cur ^= 1;
  }

  // Epilogue: D col = r (n within frag), row = g*4 + reg (j within m-frag).
  // y stores + per-nh head partials; partials combined via LDS scratch.
  float* ps = (float*)wbuf;   // psum[row(128)][nh(2)][c(2)] floats = 2 KB
  float* ob = out + (long)(bi * 128) * 774 + mlp * 258;
  floatx2 w3v[8];
#pragma unroll
  for (int nf = 0; nf < 8; nf++)
    w3v[nf] = *(const floatx2*)(w3 + ((nh * 8 + nf) * 16 + r) * 2);
#pragma unroll
  for (int mm = 0; mm < 2; mm++) {
#pragma unroll
    for (int reg = 0; reg < 4; reg++) {
      int row = jq * 32 + mm * 16 + g * 4 + reg;
      float* orow = ob + (long)row * 774 + nh * 128;
      float s0 = 0.f, s1 = 0.f;
#pragma unroll
      for (int nf = 0; nf < 8; nf++) {
        float y = acc[mm][nf][reg];
        y = y > 0.f ? y : 0.f;
        orow[nf * 16 + r] = y;
        s0 += y * w3v[nf][0];
        s1 += y * w3v[nf][1];
      }
#pragma unroll
      for (int off = 1; off < 16; off <<= 1) {
        s0 += __shfl_xor(s0, off, 64);
        s1 += __shfl_xor(s1, off, 64);
      }
      if (r == 0) {
        ps[row * 4 + nh * 2 + 0] = s0;
        ps[row * 4 + nh * 2 + 1] = s1;
      }
    }
  }
  __syncthreads();
  if (tid < 128) {
    int row = tid;
    float s0 = ps[row * 4 + 0] + ps[row * 4 + 2];
    float s1 = ps[row * 4 + 1] + ps[row * 4 + 3];
    float m = fmaxf(s0, s1);
    float e0 = __expf(s0 - m), e1 = __expf(s1 - m);
    float inv = 1.0f / (e0 + e1);
    floatx2 pr;
    pr[0] = e0 * inv;
    pr[1] = e1 * inv;
    *(floatx2*)(ob + (long)row * 774 + 256) = pr;   // 8B aligned
  }
}

// ---------------------------------------------------------------------------
// VALU fallback path (proven; used only if ws < 27 MiB). uv row-major 4 MiB.
// ---------------------------------------------------------------------------
__global__ __launch_bounds__(256) void stage1_valu(
    const float* __restrict__ P, const float* __restrict__ W1,
    float* __restrict__ uv) {
  __shared__ float at[KT][LSTRIDE];
  __shared__ float wt[KT][LSTRIDE];
  int bx = blockIdx.x;
  int m0 = (bx >> 5) * 64;
  int c0 = (bx & 31) * 64;
  int half = c0 >> 10;
  int ccol = c0 & 1023;
  int tid = threadIdx.x;
  int tm = tid >> 4, tn = tid & 15;
  int lm = tid >> 2;
  int lk4 = (tid & 3) * 4;
  int lkk = tid >> 4;
  int lc4 = (tid & 15) * 4;

  float acc[4][4] = {};

  for (int k0 = 0; k0 < 512; k0 += KT) {
    floatx4 pa = *(const floatx4*)(P + (long)(m0 + lm) * 512 + k0 + lk4);
    floatx4 wa = *(const floatx4*)(W1 + (long)(half * 512 + k0 + lkk) * 1024 + ccol + lc4);
    __syncthreads();
#pragma unroll
    for (int e = 0; e < 4; e++) at[lk4 + e][lm] = pa[e];
    *(floatx4*)&wt[lkk][lc4] = wa;
    __syncthreads();
#pragma unroll
    for (int kk = 0; kk < KT; kk++) {
      floatx4 av = *(const floatx4*)&at[kk][tm * 4];
      floatx4 wv = *(const floatx4*)&wt[kk][tn * 4];
#pragma unroll
      for (int mm = 0; mm < 4; mm++)
#pragma unroll
        for (int nn = 0; nn < 4; nn++)
          acc[mm][nn] += av[mm] * wv[nn];
    }
  }
#pragma unroll
  for (int mm = 0; mm < 4; mm++) {
    floatx4 o;
#pragma unroll
    for (int nn = 0; nn < 4; nn++) o[nn] = acc[mm][nn];
    *(floatx4*)(uv + (long)(m0 + tm * 4 + mm) * 2048 + c0 + tn * 4) = o;
  }
}

__global__ __launch_bounds__(256) void pair_valu(
    const float* __restrict__ uv, const float* __restrict__ W2,
    float* __restrict__ out, int mlp) {
  __shared__ float zt[KT][LSTRIDE];
  __shared__ float wt[KT][LSTRIDE];
  int bx = blockIdx.x;               // 4096 = 512 bi x 2 jh x 4 nb
  int nb = bx & 3;
  int jh = (bx >> 2) & 1;
  int bi = bx >> 3;
  int b = bi >> 7;
  int j0 = jh * 64;
  int n0 = nb * 64;
  int tid = threadIdx.x;
  int tm = tid >> 4, tn = tid & 15;
  int lj = tid >> 2;
  int lk4 = (tid & 3) * 4;
  int lkk = tid >> 4;
  int ln4 = (tid & 15) * 4;

  const float* urow = uv + (long)bi * 2048;
  const float* vrow = uv + (long)(b * 128 + j0 + lj) * 2048 + 1024;

  float acc[4][4] = {};

  for (int k0 = 0; k0 < 1024; k0 += KT) {
    floatx4 uu = *(const floatx4*)(urow + k0 + lk4);
    floatx4 vv = *(const floatx4*)(vrow + k0 + lk4);
    floatx4 wa = *(const floatx4*)(W2 + (long)(k0 + lkk) * 256 + n0 + ln4);
    __syncthreads();
#pragma unroll
    for (int e = 0; e < 4; e++) {
      float z = uu[e] + vv[e];
      zt[lk4 + e][lj] = z > 0.f ? z : 0.f;
    }
    *(floatx4*)&wt[lkk][ln4] = wa;
    __syncthreads();
#pragma unroll
    for (int kk = 0; kk < KT; kk++) {
      floatx4 zv = *(const floatx4*)&zt[kk][tm * 4];
      floatx4 wv = *(const floatx4*)&wt[kk][tn * 4];
#pragma unroll
      for (int mm = 0; mm < 4; mm++)
#pragma unroll
        for (int nn = 0; nn < 4; nn++)
          acc[mm][nn] += zv[mm] * wv[nn];
    }
  }
  float* ob = out + (long)(bi * 128 + j0) * 774 + mlp * 258 + n0 + tn * 4;
#pragma unroll
  for (int mm = 0; mm < 4; mm++) {
    float* orow = ob + (long)(tm * 4 + mm) * 774;
    floatx2 pa, pb;
    pa[0] = acc[mm][0] > 0.f ? acc[mm][0] : 0.f;
    pa[1] = acc[mm][1] > 0.f ? acc[mm][1] : 0.f;
    pb[0] = acc[mm][2] > 0.f ? acc[mm][2] : 0.f;
    pb[1] = acc[mm][3] > 0.f ? acc[mm][3] : 0.f;
    *(floatx2*)orow = pa;
    *(floatx2*)(orow + 2) = pb;
  }
}

__global__ __launch_bounds__(256) void head_kernel(
    const float* __restrict__ w3_0, const float* __restrict__ w3_1,
    const float* __restrict__ w3_2, float* out) {
  int wid = threadIdx.x >> 6, lane = threadIdx.x & 63;
  int r = blockIdx.x * 4 + wid;   // [0, 196608)
  int mlp = r >> 16;
  int row = r & 65535;
  const float* w3 = (mlp == 0) ? w3_0 : (mlp == 1) ? w3_1 : w3_2;
  const float* yp = out + (long)row * 774 + mlp * 258 + lane * 4;
  floatx2 ya = *(const floatx2*)yp;
  floatx2 yb = *(const floatx2*)(yp + 2);
  const float* wp = w3 + lane * 8;
  floatx4 wv0 = *(const floatx4*)wp;
  floatx4 wv1 = *(const floatx4*)(wp + 4);
  float s0 = ya[0] * wv0[0] + ya[1] * wv0[2] + yb[0] * wv1[0] + yb[1] * wv1[2];
  float s1 = ya[0] * wv0[1] + ya[1] * wv0[3] + yb[0] * wv1[1] + yb[1] * wv1[3];
#pragma unroll
  for (int off = 32; off > 0; off >>= 1) {
    s0 += __shfl_xor(s0, off, 64);
    s1 += __shfl_xor(s1, off, 64);
  }
  if (lane == 0) {
    float m = fmaxf(s0, s1);
    float e0 = __expf(s0 - m), e1 = __expf(s1 - m);
    float inv = 1.0f / (e0 + e1);
    floatx2 pr;
    pr[0] = e0 * inv;
    pr[1] = e1 * inv;
    *(floatx2*)(out + (long)row * 774 + mlp * 258 + 256) = pr;
  }
}

extern "C" void kernel_launch(void* const* d_in, const int* in_sizes, int n_in,
                              void* d_out, int out_size, void* d_ws, size_t ws_size,
                              hipStream_t stream) {
  const float* para = (const float*)d_in[0];
  const float* Wf1  = (const float*)d_in[1];
  const float* Wf2  = (const float*)d_in[2];
  const float* w3   = (const float*)d_in[3];
  const float* Wh1a = (const float*)d_in[4];
  const float* Wh1b = (const float*)d_in[5];
  const float* wl1  = (const float*)d_in[6];
  const float* Wh2a = (const float*)d_in[7];
  const float* Wh2b = (const float*)d_in[8];
  const float* wl2  = (const float*)d_in[9];

  float* outp = (float*)d_out;   // f32 [4*128*128][774]

  if (ws_size >= (size_t)27 * MB) {
    float* uF_all = (float*)d_ws;                                       // 6 MiB
    float* vF_all = (float*)((char*)d_ws + 6 * MB);                     // 6 MiB
    unsigned short* w2f_all = (unsigned short*)((char*)d_ws + 12 * MB); // 3 MiB
    unsigned short* w1f_all = (unsigned short*)((char*)d_ws + 15 * MB); // 12 MiB
    prep_all<<<1920, 256, 0, stream>>>(Wf1, Wh1a, Wh2a, Wf2, Wh1b, Wh2b,
                                       w1f_all, w2f_all);
    stage1_mfma3<<<1536, 256, 0, stream>>>(para, w1f_all, uF_all, vF_all);
    pair_mfma3<<<1536, 512, 0, stream>>>(uF_all, vF_all, w2f_all,
                                         w3, wl1, wl2, outp);
  } else {
    const float* W1s[3] = {Wf1, Wh1a, Wh2a};
    const float* W2s[3] = {Wf2, Wh1b, Wh2b};
    float* uv = (float*)d_ws;   // 4 MiB
    for (int mlp = 0; mlp < 3; mlp++) {
      stage1_valu<<<256, 256, 0, stream>>>(para, W1s[mlp], uv);
      pair_valu<<<4096, 256, 0, stream>>>(uv, W2s[mlp], outp, mlp);
    }
    head_kernel<<<49152, 256, 0, stream>>>(w3, wl1, wl2, outp);
  }
}